// Round 9
// baseline (397.039 us; speedup 1.0000x reference)
//
#include <hip/hip_runtime.h>
#include <hip/hip_bf16.h>

typedef _Float16 half8 __attribute__((ext_vector_type(8)));
typedef float f32x4 __attribute__((ext_vector_type(4)));

// ---------------- helpers ----------------
static __device__ __forceinline__ float bf2f_lo(unsigned u) {
    return __uint_as_float(u << 16);
}
static __device__ __forceinline__ float bf2f_hi(unsigned u) {
    return __uint_as_float(u & 0xffff0000u);
}
static __device__ __forceinline__ unsigned f2bf_rne_bits(float f) {
    unsigned u = __float_as_uint(f);
    return u + 0x7fffu + ((u >> 16) & 1u);
}
static __device__ __forceinline__ unsigned pack_bf2(float a, float b) {
    return (f2bf_rne_bits(a) >> 16) | (f2bf_rne_bits(b) & 0xffff0000u);
}

// ================= CSR build: two-level bucket sort (split, proven) ==========
#define CHUNK 4096

__global__ void kb_count(const int* __restrict__ dst, int* bucketCount,
                         int E, int T, int NBK) {
    __shared__ int cnt[256];
    const int tid = threadIdx.x;
    const int beg = blockIdx.x * CHUNK;
    const int end = min(beg + CHUNK, T);
    cnt[tid] = 0;
    __syncthreads();
    for (int i = beg + tid; i < end; i += 256) {
        int d = (i < E) ? dst[i] : (i - E);
        atomicAdd(&cnt[d >> 8], 1);
    }
    __syncthreads();
    if (tid < NBK && cnt[tid] > 0) atomicAdd(&bucketCount[tid], cnt[tid]);
}

__global__ void kb_scan(const int* __restrict__ bucketCount, int* bucketBase,
                        int* bucketCursor, int* row_ptr, int NBK, int N, int total) {
    __shared__ int sm[256];
    const int tid = threadIdx.x;
    int v = (tid < NBK) ? bucketCount[tid] : 0;
    sm[tid] = v;
    __syncthreads();
    for (int off = 1; off < 256; off <<= 1) {
        int t = (tid >= off) ? sm[tid - off] : 0;
        __syncthreads();
        sm[tid] += t;
        __syncthreads();
    }
    if (tid < NBK) {
        int ex = sm[tid] - v;
        bucketBase[tid] = ex;
        bucketCursor[tid] = ex;
    }
    if (tid == 0) {
        bucketBase[NBK] = total;
        row_ptr[N] = total;
    }
}

__global__ void kb_place(const int* __restrict__ src, const int* __restrict__ dst,
                         int* bucketCursor, unsigned* __restrict__ barr,
                         int E, int T, int NBK) {
    __shared__ int cnt[256];
    __shared__ int wb[256];
    const int tid = threadIdx.x;
    const int beg = blockIdx.x * CHUNK;
    const int end = min(beg + CHUNK, T);
    cnt[tid] = 0;
    __syncthreads();
    for (int i = beg + tid; i < end; i += 256) {
        int d = (i < E) ? dst[i] : (i - E);
        atomicAdd(&cnt[d >> 8], 1);
    }
    __syncthreads();
    if (tid < NBK) {
        int c = cnt[tid];
        wb[tid] = (c > 0) ? atomicAdd(&bucketCursor[tid], c) : 0;
    }
    __syncthreads();
    cnt[tid] = 0;
    __syncthreads();
    for (int i = beg + tid; i < end; i += 256) {
        int s, d;
        if (i < E) { s = src[i]; d = dst[i]; }
        else       { s = i - E;  d = s; }
        int g = d >> 8;
        unsigned pk = (unsigned)s | ((unsigned)(d & 255) << 16);
        int r = atomicAdd(&cnt[g], 1);
        barr[wb[g] + r] = pk;
    }
}

// ---------------- MFMA GEMM body: h = A @ W (fp32 in, bf16 out) --------------
// Interleaved output [N][64] dwords (256B rows), gathered coalesced by aggr.
// R14: h stores go through an LDS transpose (REUSING Wt's dead LDS space) so
// every global store instruction writes 1KB contiguous (4 full rows) instead
// of 64 x 8B at 256B stride — kills the 6x RMW write amplification measured
// in R13 (WRITE_SIZE 129MB for 22MB of logical writes, VALUBusy 4%).
static __device__ void gemm_body(char* smem /* 34816B */, int bid, int GB,
                                 const float* __restrict__ A, const float* __restrict__ W,
                                 const float* __restrict__ a_src, const float* __restrict__ a_dst,
                                 unsigned* __restrict__ Hout,
                                 float* __restrict__ asrc_o, float* __restrict__ adst_o,
                                 int nrows, int ntiles) {
    _Float16* Wt = (_Float16*)smem;   // [128 c][136 k] halves (272B row, b128-aligned)
    const int tid = threadIdx.x;
    // stage W^T (fp32 [k][c] -> fp16 [c][k]), coalesced global reads
    for (int idx = tid; idx < 128 * 128 / 4; idx += 256) {
        int k = idx >> 5;            // 32 float4 per k-row
        int c4 = (idx & 31) * 4;
        float4 v = *(const float4*)&W[(size_t)k * 128 + c4];
        Wt[(c4 + 0) * 136 + k] = (_Float16)v.x;
        Wt[(c4 + 1) * 136 + k] = (_Float16)v.y;
        Wt[(c4 + 2) * 136 + k] = (_Float16)v.z;
        Wt[(c4 + 3) * 136 + k] = (_Float16)v.w;
    }
    __syncthreads();
    const int lane = tid & 63;
    const int m = lane & 15, quad = lane >> 4;

    // W fragments -> registers: wf[ks][ct] = A-op[mA=lane&15][k=quad*8+j]
    half8 wf[4][8];
#pragma unroll
    for (int ks = 0; ks < 4; ++ks)
#pragma unroll
        for (int ct = 0; ct < 8; ++ct)
            wf[ks][ct] = *(half8*)&Wt[(ct * 16 + m) * 136 + ks * 32 + quad * 8];

    // Wt is DEAD from here; reuse its LDS as per-wave store-staging tiles.
    __syncthreads();
    // per-wave region: 16 rows x 68 dwords (272B stride: banks (4m+c)%32, ~2-way)
    unsigned* st = (unsigned*)smem + (tid >> 6) * (16 * 68);

    const int wv = (bid * 256 + tid) >> 6;
    const int nwaves = GB * 4;
    for (int t = wv; t < ntiles; t += nwaves) {
        const int row = t * 16 + m;
        const int rc = min(row, nrows - 1);
        const float* ap = A + (size_t)rc * 128;
        f32x4 acc[8];
#pragma unroll
        for (int ct = 0; ct < 8; ++ct) acc[ct] = (f32x4){0.f, 0.f, 0.f, 0.f};
#pragma unroll
        for (int ks = 0; ks < 4; ++ks) {
            float4 x0 = *(const float4*)&ap[ks * 32 + quad * 8];
            float4 x1 = *(const float4*)&ap[ks * 32 + quad * 8 + 4];
            half8 af;
            af[0] = (_Float16)x0.x; af[1] = (_Float16)x0.y;
            af[2] = (_Float16)x0.z; af[3] = (_Float16)x0.w;
            af[4] = (_Float16)x1.x; af[5] = (_Float16)x1.y;
            af[6] = (_Float16)x1.z; af[7] = (_Float16)x1.w;
#pragma unroll
            for (int ct = 0; ct < 8; ++ct)
                acc[ct] = __builtin_amdgcn_mfma_f32_16x16x32_f16(wf[ks][ct], af, acc[ct], 0, 0, 0);
        }
        // h store, stage 1: packed bf16 pairs -> LDS (ds_write_b64, in-order per wave)
#pragma unroll
        for (int ct = 0; ct < 8; ++ct) {
            uint2 o;
            o.x = pack_bf2(acc[ct][0], acc[ct][1]);
            o.y = pack_bf2(acc[ct][2], acc[ct][3]);
            *(uint2*)&st[m * 68 + ct * 8 + quad * 2] = o;
        }
        // h store, stage 2: read back row-major, 1KB contiguous per instruction
#pragma unroll
        for (int i = 0; i < 4; ++i) {
            int rl = i * 4 + (lane >> 4);          // local row 0..15
            int grow = t * 16 + rl;
            uint4 v = *(uint4*)&st[rl * 68 + (lane & 15) * 4];
            if (grow < nrows)
                *(uint4*)&Hout[(size_t)grow * 64 + (lane & 15) * 4] = v;
        }
        // alpha partials (fp32, pre-rounding); a_src/a_dst are L1-hot (512B)
        float ps[4] = {0.f, 0.f, 0.f, 0.f}, pd[4] = {0.f, 0.f, 0.f, 0.f};
#pragma unroll
        for (int ct = 0; ct < 8; ++ct) {
            int hh = ct >> 1;
#pragma unroll
            for (int r = 0; r < 4; ++r) {
                int c = ct * 16 + quad * 4 + r;
                ps[hh] += acc[ct][r] * a_src[c];
                pd[hh] += acc[ct][r] * a_dst[c];
            }
        }
#pragma unroll
        for (int hh = 0; hh < 4; ++hh) {
            ps[hh] += __shfl_xor(ps[hh], 16); ps[hh] += __shfl_xor(ps[hh], 32);
            pd[hh] += __shfl_xor(pd[hh], 16); pd[hh] += __shfl_xor(pd[hh], 32);
        }
        if (row < nrows) {
            asrc_o[(size_t)row * 4 + quad] = ps[quad];
            adst_o[(size_t)row * 4 + quad] = pd[quad];
        }
    }
}

// ---------------- merged: CSR finalize (blocks < NBK) || gemm layer 1 --------
// SAFE role split: no shared data, no cross-block sync; both roles depend only
// on stream-order-completed kernels. Dispatch order irrelevant to correctness.
__global__ void k_csr_gemm(const unsigned* __restrict__ barr, const int* __restrict__ bucketBase,
                           int* __restrict__ row_ptr, int* __restrict__ col, int N, int NBK,
                           const float* __restrict__ x, const float* __restrict__ W1,
                           const float* __restrict__ a_src1, const float* __restrict__ a_dst1,
                           unsigned* __restrict__ h_bf,
                           float* __restrict__ asrc, float* __restrict__ adst,
                           int ntiles, int GB) {
    __shared__ __align__(16) char smem[128 * 136 * 2];   // 34.8 KB, role-reused
    const int tid = threadIdx.x;
    const int b = blockIdx.x;

    if (b >= NBK) {   // ---- gemm role (layer 1) ----
        gemm_body(smem, b - NBK, GB, x, W1, a_src1, a_dst1,
                  h_bf, asrc, adst, N, ntiles);
        return;
    }

    // ---- csr-finalize role (kb_csr body) ----
    int* cnt = (int*)smem;          // [256]
    int* sm  = (int*)smem + 256;    // [256]
    int* cur = (int*)smem + 512;    // [256]
    const int beg = bucketBase[b];
    const int end = bucketBase[b + 1];
    cnt[tid] = 0;
    __syncthreads();
    for (int i = beg + tid; i < end; i += 256)
        atomicAdd(&cnt[barr[i] >> 16], 1);
    __syncthreads();
    int v = cnt[tid];
    sm[tid] = v;
    __syncthreads();
    for (int off = 1; off < 256; off <<= 1) {
        int t = (tid >= off) ? sm[tid - off] : 0;
        __syncthreads();
        sm[tid] += t;
        __syncthreads();
    }
    int ex = sm[tid] - v;
    int n = b * 256 + tid;
    if (n < N) row_ptr[n] = beg + ex;
    cur[tid] = beg + ex;
    __syncthreads();
    for (int i = beg + tid; i < end; i += 256) {
        unsigned p = barr[i];
        int pos = atomicAdd(&cur[p >> 16], 1);
        col[pos] = (int)(p & 0xFFFFu);
    }
}

// ---------------- standalone gemm (layer 2) ----------------
__launch_bounds__(256)
__global__ void k_gemm(const float* __restrict__ A, const float* __restrict__ W,
                       const float* __restrict__ a_src, const float* __restrict__ a_dst,
                       unsigned* __restrict__ Hout,
                       float* __restrict__ asrc_o, float* __restrict__ adst_o,
                       int nrows, int ntiles) {
    __shared__ __align__(16) char smem[128 * 136 * 2];
    gemm_body(smem, blockIdx.x, gridDim.x, A, W, a_src, a_dst,
              Hout, asrc_o, adst_o, nrows, ntiles);
}

// ---------------- fused softmax-aggregate + bias + ELU (R6, proven 59us) -----
#define BAT 16
__launch_bounds__(256)
__global__ void k_aggr(const unsigned* __restrict__ h,
                       const float* __restrict__ asrc, const float* __restrict__ adst,
                       const float* __restrict__ bias,
                       const int* __restrict__ row_ptr, const int* __restrict__ col,
                       float* __restrict__ out, int N) {
    const int lane = threadIdx.x & 63;
    const int d = blockIdx.x * 4 + (threadIdx.x >> 6);
    if (d >= N) return;
    const int eb  = lane >> 2;
    const int hp  = lane & 3;
    const int hdc = lane >> 4;
    const float adv = adst[(size_t)d * 4 + hp];
    const int beg = row_ptr[d];
    const int end = row_ptr[d + 1];

    float ac0 = 0.f, ac1 = 0.f, sp = 0.f;
    int cv = 0;
    { int idx = beg + eb; if (idx < end) cv = col[idx]; }

    for (int j = beg; j < end; j += BAT) {
        int cvn = 0;
        { int idx = j + BAT + eb; if (idx < end) cvn = col[idx]; }

        float a = asrc[(size_t)(unsigned)cv * 4 + hp];
        float e = a + adv;
        e = fmaxf(e, 0.2f * e);
        float p = (j + eb < end) ? __expf(e) : 0.f;
        sp += p;

        unsigned u[BAT];
#pragma unroll
        for (int k = 0; k < BAT; ++k) {
            int sk = __builtin_amdgcn_readlane(cv, 4 * k);
            u[k] = h[(size_t)(unsigned)sk * 64 + lane];
        }
#pragma unroll
        for (int k = 0; k < BAT; ++k) {
            float pk = __shfl(p, 4 * k + hdc);
            ac0 = fmaf(pk, bf2f_lo(u[k]), ac0);
            ac1 = fmaf(pk, bf2f_hi(u[k]), ac1);
        }
        cv = cvn;
    }

    sp += __shfl_xor(sp, 4);
    sp += __shfl_xor(sp, 8);
    sp += __shfl_xor(sp, 16);
    sp += __shfl_xor(sp, 32);
    float spv = __shfl(sp, hdc);
    float inv = 1.f / spv;

    int c = 2 * lane;
    float v0 = ac0 * inv + bias[c];
    float v1 = ac1 * inv + bias[c + 1];
    v0 = (v0 > 0.f) ? v0 : (__expf(v0) - 1.f);
    v1 = (v1 > 0.f) ? v1 : (__expf(v1) - 1.f);
    *(float2*)&out[(size_t)d * 128 + c] = make_float2(v0, v1);
}

// ---------------- launch ----------------
extern "C" void kernel_launch(void* const* d_in, const int* in_sizes, int n_in,
                              void* d_out, int out_size, void* d_ws, size_t ws_size,
                              hipStream_t stream) {
    const float* x      = (const float*)d_in[0];
    const int*   ei     = (const int*)d_in[1];
    const float* W1     = (const float*)d_in[2];
    const float* a_src1 = (const float*)d_in[3];
    const float* a_dst1 = (const float*)d_in[4];
    const float* b1     = (const float*)d_in[5];
    const float* W2     = (const float*)d_in[6];
    const float* a_src2 = (const float*)d_in[7];
    const float* a_dst2 = (const float*)d_in[8];
    const float* b2     = (const float*)d_in[9];

    const int N = in_sizes[0] / 128;
    const int E = in_sizes[1] / 2;
    const int T = E + N;
    const int NBK = (N + 255) / 256;
    const int* src = ei;
    const int* dst = ei + E;

    char* w = (char*)d_ws;
    auto alloc = [&](size_t bytes) -> char* {
        char* p = w;
        w += (bytes + 255) & ~(size_t)255;
        return p;
    };
    unsigned* h_bf    = (unsigned*)alloc((size_t)N * 64 * 4);
    float*    o1      = (float*)alloc((size_t)N * 128 * 4);
    float*    asrc    = (float*)alloc((size_t)N * 4 * 4);
    float*    adst    = (float*)alloc((size_t)N * 4 * 4);
    int*      row_ptr = (int*)alloc((size_t)(N + 1) * 4);
    int*      col     = (int*)alloc((size_t)T * 4);
    int*      bCount  = (int*)alloc((size_t)NBK * 4);
    int*      bBase   = (int*)alloc((size_t)(NBK + 1) * 4);
    int*      bCursor = (int*)alloc((size_t)NBK * 4);
    unsigned* barr    = (unsigned*)o1;   // alias: dead before o1 written
    (void)ws_size; (void)n_in; (void)out_size;

    const int PB = (T + CHUNK - 1) / CHUNK;
    const int ntiles = (N + 15) / 16;
    const int GB = 512;               // gemm blocks (2048 waves)
    const int AB = (N + 3) / 4;

    // 8 ops: memset, count, scan, place, [csr || gemm1], aggr1, gemm2, aggr2
    hipMemsetAsync(bCount, 0, (size_t)NBK * 4, stream);
    hipLaunchKernelGGL(kb_count, dim3(PB), dim3(256), 0, stream, dst, bCount, E, T, NBK);
    hipLaunchKernelGGL(kb_scan, dim3(1), dim3(256), 0, stream, bCount, bBase, bCursor, row_ptr, NBK, N, T);
    hipLaunchKernelGGL(kb_place, dim3(PB), dim3(256), 0, stream, src, dst, bCursor, barr, E, T, NBK);
    hipLaunchKernelGGL(k_csr_gemm, dim3(NBK + GB), dim3(256), 0, stream,
                       barr, bBase, row_ptr, col, N, NBK,
                       x, W1, a_src1, a_dst1, h_bf, asrc, adst, ntiles, GB);
    hipLaunchKernelGGL(k_aggr, dim3(AB), dim3(256), 0, stream, h_bf, asrc, adst, b1, row_ptr, col, o1, N);
    hipLaunchKernelGGL(k_gemm, dim3(GB), dim3(256), 0, stream, o1, W2, a_src2, a_dst2, h_bf, asrc, adst, N, ntiles);
    hipLaunchKernelGGL(k_aggr, dim3(AB), dim3(256), 0, stream, h_bf, asrc, adst, b2, row_ptr, col, (float*)d_out, N);
}

// Round 10
// 285.396 us; speedup vs baseline: 1.3912x; 1.3912x over previous
//
#include <hip/hip_runtime.h>
#include <hip/hip_bf16.h>

typedef _Float16 half8 __attribute__((ext_vector_type(8)));
typedef float f32x4 __attribute__((ext_vector_type(4)));

// ---------------- helpers ----------------
static __device__ __forceinline__ float bf2f_lo(unsigned u) {
    return __uint_as_float(u << 16);
}
static __device__ __forceinline__ float bf2f_hi(unsigned u) {
    return __uint_as_float(u & 0xffff0000u);
}
static __device__ __forceinline__ unsigned f2bf_rne_bits(float f) {
    unsigned u = __float_as_uint(f);
    return u + 0x7fffu + ((u >> 16) & 1u);
}
static __device__ __forceinline__ unsigned pack_bf2(float a, float b) {
    return (f2bf_rne_bits(a) >> 16) | (f2bf_rne_bits(b) & 0xffff0000u);
}

// ================= CSR build: two-level bucket sort (split, proven) ==========
#define CHUNK 4096

// count role (blocks < PB) + W-transpose prep role (blocks PB, PB+1).
// Roles share NO data and have NO cross-block sync -> dispatch-order-proof.
// Prep: W (fp32 [k][c]) -> WT (fp16 [c][k], uint4-packed) ONCE per layer, so
// every gemm block stages via 2048 coalesced loads + 2048 ds_write_b128
// instead of 16384 loads + 65536 scalar ds_write_b16 (R14 post-mortem: that
// per-block re-transpose was ~42M instructions of latency-exposed work).
__global__ void kb_count_prep(const int* __restrict__ dst, int* bucketCount,
                              int E, int T, int NBK, int PB,
                              const float* __restrict__ W1, const float* __restrict__ W2,
                              uint4* __restrict__ wt1, uint4* __restrict__ wt2) {
    __shared__ __align__(16) char smem[128 * 136 * 2];   // 34.8 KB
    const int tid = threadIdx.x;
    const int b = blockIdx.x;

    if (b >= PB) {   // ---- prep role: transpose one W ----
        const float* W = (b == PB) ? W1 : W2;
        uint4* out = (b == PB) ? wt1 : wt2;
        _Float16* Wt = (_Float16*)smem;   // [c][136 k] halves
        for (int idx = tid; idx < 128 * 128 / 4; idx += 256) {
            int k = idx >> 5;
            int c4 = (idx & 31) * 4;
            float4 v = *(const float4*)&W[(size_t)k * 128 + c4];
            Wt[(c4 + 0) * 136 + k] = (_Float16)v.x;
            Wt[(c4 + 1) * 136 + k] = (_Float16)v.y;
            Wt[(c4 + 2) * 136 + k] = (_Float16)v.z;
            Wt[(c4 + 3) * 136 + k] = (_Float16)v.w;
        }
        __syncthreads();
        // write WT[c][k] packed: uint4 idx -> c = idx>>4, k0 = (idx&15)*8
#pragma unroll
        for (int it = 0; it < 8; ++it) {
            int idx = tid + it * 256;
            int c = idx >> 4, k0 = (idx & 15) * 8;
            out[idx] = *(uint4*)&Wt[c * 136 + k0];
        }
        return;
    }

    // ---- count role ----
    int* cnt = (int*)smem;
    const int beg = b * CHUNK;
    const int end = min(beg + CHUNK, T);
    cnt[tid] = 0;
    __syncthreads();
    for (int i = beg + tid; i < end; i += 256) {
        int d = (i < E) ? dst[i] : (i - E);
        atomicAdd(&cnt[d >> 8], 1);
    }
    __syncthreads();
    if (tid < NBK && cnt[tid] > 0) atomicAdd(&bucketCount[tid], cnt[tid]);
}

__global__ void kb_scan(const int* __restrict__ bucketCount, int* bucketBase,
                        int* bucketCursor, int* row_ptr, int NBK, int N, int total) {
    __shared__ int sm[256];
    const int tid = threadIdx.x;
    int v = (tid < NBK) ? bucketCount[tid] : 0;
    sm[tid] = v;
    __syncthreads();
    for (int off = 1; off < 256; off <<= 1) {
        int t = (tid >= off) ? sm[tid - off] : 0;
        __syncthreads();
        sm[tid] += t;
        __syncthreads();
    }
    if (tid < NBK) {
        int ex = sm[tid] - v;
        bucketBase[tid] = ex;
        bucketCursor[tid] = ex;
    }
    if (tid == 0) {
        bucketBase[NBK] = total;
        row_ptr[N] = total;
    }
}

__global__ void kb_place(const int* __restrict__ src, const int* __restrict__ dst,
                         int* bucketCursor, unsigned* __restrict__ barr,
                         int E, int T, int NBK) {
    __shared__ int cnt[256];
    __shared__ int wb[256];
    const int tid = threadIdx.x;
    const int beg = blockIdx.x * CHUNK;
    const int end = min(beg + CHUNK, T);
    cnt[tid] = 0;
    __syncthreads();
    for (int i = beg + tid; i < end; i += 256) {
        int d = (i < E) ? dst[i] : (i - E);
        atomicAdd(&cnt[d >> 8], 1);
    }
    __syncthreads();
    if (tid < NBK) {
        int c = cnt[tid];
        wb[tid] = (c > 0) ? atomicAdd(&bucketCursor[tid], c) : 0;
    }
    __syncthreads();
    cnt[tid] = 0;
    __syncthreads();
    for (int i = beg + tid; i < end; i += 256) {
        int s, d;
        if (i < E) { s = src[i]; d = dst[i]; }
        else       { s = i - E;  d = s; }
        int g = d >> 8;
        unsigned pk = (unsigned)s | ((unsigned)(d & 255) << 16);
        int r = atomicAdd(&cnt[g], 1);
        barr[wb[g] + r] = pk;
    }
}

__global__ void kb_csr(const unsigned* __restrict__ barr, const int* __restrict__ bucketBase,
                       int* __restrict__ row_ptr, int* __restrict__ col, int N) {
    __shared__ int cnt[256];
    __shared__ int sm[256];
    __shared__ int cur[256];
    const int tid = threadIdx.x;
    const int b = blockIdx.x;
    const int beg = bucketBase[b];
    const int end = bucketBase[b + 1];
    cnt[tid] = 0;
    __syncthreads();
    for (int i = beg + tid; i < end; i += 256)
        atomicAdd(&cnt[barr[i] >> 16], 1);
    __syncthreads();
    int v = cnt[tid];
    sm[tid] = v;
    __syncthreads();
    for (int off = 1; off < 256; off <<= 1) {
        int t = (tid >= off) ? sm[tid - off] : 0;
        __syncthreads();
        sm[tid] += t;
        __syncthreads();
    }
    int ex = sm[tid] - v;
    int n = b * 256 + tid;
    if (n < N) row_ptr[n] = beg + ex;
    cur[tid] = beg + ex;
    __syncthreads();
    for (int i = beg + tid; i < end; i += 256) {
        unsigned p = barr[i];
        int pos = atomicAdd(&cur[p >> 16], 1);
        col[pos] = (int)(p & 0xFFFFu);
    }
}

// ---------------- MFMA GEMM: h = A @ WT^T (fp16 WT precomputed) --------------
// Interleaved output [N][64] dwords (256B rows), gathered coalesced by aggr.
// Staging: 8 x (coalesced uint4 load from L2-hot WT + ds_write_b128).
__launch_bounds__(256)
__global__ void k_gemm(const float* __restrict__ A, const uint4* __restrict__ WT,
                       const float* __restrict__ a_src, const float* __restrict__ a_dst,
                       unsigned* __restrict__ Hout,
                       float* __restrict__ asrc_o, float* __restrict__ adst_o,
                       int nrows, int ntiles) {
    __shared__ __align__(16) _Float16 Wt[128 * 136];  // [c][k], 272B row stride
    const int tid = threadIdx.x;
#pragma unroll
    for (int it = 0; it < 8; ++it) {
        int idx = tid + it * 256;
        int c = idx >> 4, k0 = (idx & 15) * 8;
        *(uint4*)&Wt[c * 136 + k0] = WT[idx];
    }
    __syncthreads();
    const int lane = tid & 63;
    const int m = lane & 15, quad = lane >> 4;

    // W fragments -> registers: wf[ks][ct] = A-op[mA=lane&15][k=quad*8+j]
    half8 wf[4][8];
#pragma unroll
    for (int ks = 0; ks < 4; ++ks)
#pragma unroll
        for (int ct = 0; ct < 8; ++ct)
            wf[ks][ct] = *(half8*)&Wt[(ct * 16 + m) * 136 + ks * 32 + quad * 8];

    const int wv = (blockIdx.x * 256 + tid) >> 6;
    const int nwaves = gridDim.x * 4;
    for (int t = wv; t < ntiles; t += nwaves) {
        const int row = t * 16 + m;
        const int rc = min(row, nrows - 1);
        const float* ap = A + (size_t)rc * 128;
        f32x4 acc[8];
#pragma unroll
        for (int ct = 0; ct < 8; ++ct) acc[ct] = (f32x4){0.f, 0.f, 0.f, 0.f};
#pragma unroll
        for (int ks = 0; ks < 4; ++ks) {
            float4 x0 = *(const float4*)&ap[ks * 32 + quad * 8];
            float4 x1 = *(const float4*)&ap[ks * 32 + quad * 8 + 4];
            half8 af;
            af[0] = (_Float16)x0.x; af[1] = (_Float16)x0.y;
            af[2] = (_Float16)x0.z; af[3] = (_Float16)x0.w;
            af[4] = (_Float16)x1.x; af[5] = (_Float16)x1.y;
            af[6] = (_Float16)x1.z; af[7] = (_Float16)x1.w;
#pragma unroll
            for (int ct = 0; ct < 8; ++ct)
                acc[ct] = __builtin_amdgcn_mfma_f32_16x16x32_f16(wf[ks][ct], af, acc[ct], 0, 0, 0);
        }
        // h store: lane's 4 consecutive cols per ct -> 2 packed uints
        if (row < nrows) {
#pragma unroll
            for (int ct = 0; ct < 8; ++ct) {
                uint2 o;
                o.x = pack_bf2(acc[ct][0], acc[ct][1]);
                o.y = pack_bf2(acc[ct][2], acc[ct][3]);
                *(uint2*)&Hout[(size_t)row * 64 + ct * 8 + quad * 2] = o;
            }
        }
        // alpha partials (fp32, pre-rounding); a_src/a_dst are L1-hot (512B)
        float ps[4] = {0.f, 0.f, 0.f, 0.f}, pd[4] = {0.f, 0.f, 0.f, 0.f};
#pragma unroll
        for (int ct = 0; ct < 8; ++ct) {
            int hh = ct >> 1;
#pragma unroll
            for (int r = 0; r < 4; ++r) {
                int c = ct * 16 + quad * 4 + r;
                ps[hh] += acc[ct][r] * a_src[c];
                pd[hh] += acc[ct][r] * a_dst[c];
            }
        }
#pragma unroll
        for (int hh = 0; hh < 4; ++hh) {
            ps[hh] += __shfl_xor(ps[hh], 16); ps[hh] += __shfl_xor(ps[hh], 32);
            pd[hh] += __shfl_xor(pd[hh], 16); pd[hh] += __shfl_xor(pd[hh], 32);
        }
        if (row < nrows) {
            asrc_o[(size_t)row * 4 + quad] = ps[quad];
            adst_o[(size_t)row * 4 + quad] = pd[quad];
        }
    }
}

// ---------------- fused softmax-aggregate + bias + ELU (R6, proven 59us) -----
#define BAT 16
__launch_bounds__(256)
__global__ void k_aggr(const unsigned* __restrict__ h,
                       const float* __restrict__ asrc, const float* __restrict__ adst,
                       const float* __restrict__ bias,
                       const int* __restrict__ row_ptr, const int* __restrict__ col,
                       float* __restrict__ out, int N) {
    const int lane = threadIdx.x & 63;
    const int d = blockIdx.x * 4 + (threadIdx.x >> 6);
    if (d >= N) return;
    const int eb  = lane >> 2;
    const int hp  = lane & 3;
    const int hdc = lane >> 4;
    const float adv = adst[(size_t)d * 4 + hp];
    const int beg = row_ptr[d];
    const int end = row_ptr[d + 1];

    float ac0 = 0.f, ac1 = 0.f, sp = 0.f;
    int cv = 0;
    { int idx = beg + eb; if (idx < end) cv = col[idx]; }

    for (int j = beg; j < end; j += BAT) {
        int cvn = 0;
        { int idx = j + BAT + eb; if (idx < end) cvn = col[idx]; }

        float a = asrc[(size_t)(unsigned)cv * 4 + hp];
        float e = a + adv;
        e = fmaxf(e, 0.2f * e);
        float p = (j + eb < end) ? __expf(e) : 0.f;
        sp += p;

        unsigned u[BAT];
#pragma unroll
        for (int k = 0; k < BAT; ++k) {
            int sk = __builtin_amdgcn_readlane(cv, 4 * k);
            u[k] = h[(size_t)(unsigned)sk * 64 + lane];
        }
#pragma unroll
        for (int k = 0; k < BAT; ++k) {
            float pk = __shfl(p, 4 * k + hdc);
            ac0 = fmaf(pk, bf2f_lo(u[k]), ac0);
            ac1 = fmaf(pk, bf2f_hi(u[k]), ac1);
        }
        cv = cvn;
    }

    sp += __shfl_xor(sp, 4);
    sp += __shfl_xor(sp, 8);
    sp += __shfl_xor(sp, 16);
    sp += __shfl_xor(sp, 32);
    float spv = __shfl(sp, hdc);
    float inv = 1.f / spv;

    int c = 2 * lane;
    float v0 = ac0 * inv + bias[c];
    float v1 = ac1 * inv + bias[c + 1];
    v0 = (v0 > 0.f) ? v0 : (__expf(v0) - 1.f);
    v1 = (v1 > 0.f) ? v1 : (__expf(v1) - 1.f);
    *(float2*)&out[(size_t)d * 128 + c] = make_float2(v0, v1);
}

// ---------------- launch ----------------
extern "C" void kernel_launch(void* const* d_in, const int* in_sizes, int n_in,
                              void* d_out, int out_size, void* d_ws, size_t ws_size,
                              hipStream_t stream) {
    const float* x      = (const float*)d_in[0];
    const int*   ei     = (const int*)d_in[1];
    const float* W1     = (const float*)d_in[2];
    const float* a_src1 = (const float*)d_in[3];
    const float* a_dst1 = (const float*)d_in[4];
    const float* b1     = (const float*)d_in[5];
    const float* W2     = (const float*)d_in[6];
    const float* a_src2 = (const float*)d_in[7];
    const float* a_dst2 = (const float*)d_in[8];
    const float* b2     = (const float*)d_in[9];

    const int N = in_sizes[0] / 128;
    const int E = in_sizes[1] / 2;
    const int T = E + N;
    const int NBK = (N + 255) / 256;
    const int* src = ei;
    const int* dst = ei + E;

    char* w = (char*)d_ws;
    auto alloc = [&](size_t bytes) -> char* {
        char* p = w;
        w += (bytes + 255) & ~(size_t)255;
        return p;
    };
    unsigned* h_bf    = (unsigned*)alloc((size_t)N * 64 * 4);
    float*    o1      = (float*)alloc((size_t)N * 128 * 4);
    float*    asrc    = (float*)alloc((size_t)N * 4 * 4);
    float*    adst    = (float*)alloc((size_t)N * 4 * 4);
    int*      row_ptr = (int*)alloc((size_t)(N + 1) * 4);
    int*      col     = (int*)alloc((size_t)T * 4);
    int*      bCount  = (int*)alloc((size_t)NBK * 4);
    int*      bBase   = (int*)alloc((size_t)(NBK + 1) * 4);
    int*      bCursor = (int*)alloc((size_t)NBK * 4);
    uint4*    wt1     = (uint4*)alloc(128 * 128 * 2);   // fp16 W^T, 32KB
    uint4*    wt2     = (uint4*)alloc(128 * 128 * 2);
    unsigned* barr    = (unsigned*)o1;   // alias: dead before o1 written
    (void)ws_size; (void)n_in; (void)out_size;

    const int PB = (T + CHUNK - 1) / CHUNK;
    const int ntiles = (N + 15) / 16;
    const int GB = 512;               // grid-stride over tiles (2048 waves)
    const int AB = (N + 3) / 4;

    // 9 ops: memset, count+prep, scan, place, csr, gemm1, aggr1, gemm2, aggr2
    hipMemsetAsync(bCount, 0, (size_t)NBK * 4, stream);
    hipLaunchKernelGGL(kb_count_prep, dim3(PB + 2), dim3(256), 0, stream,
                       dst, bCount, E, T, NBK, PB, W1, W2, wt1, wt2);
    hipLaunchKernelGGL(kb_scan, dim3(1), dim3(256), 0, stream, bCount, bBase, bCursor, row_ptr, NBK, N, T);
    hipLaunchKernelGGL(kb_place, dim3(PB), dim3(256), 0, stream, src, dst, bCursor, barr, E, T, NBK);
    hipLaunchKernelGGL(kb_csr, dim3(NBK), dim3(256), 0, stream, barr, bBase, row_ptr, col, N);
    hipLaunchKernelGGL(k_gemm, dim3(GB), dim3(256), 0, stream, x, wt1, a_src1, a_dst1, h_bf, asrc, adst, N, ntiles);
    hipLaunchKernelGGL(k_aggr, dim3(AB), dim3(256), 0, stream, h_bf, asrc, adst, b1, row_ptr, col, o1, N);
    hipLaunchKernelGGL(k_gemm, dim3(GB), dim3(256), 0, stream, o1, wt2, a_src2, a_dst2, h_bf, asrc, adst, N, ntiles);
    hipLaunchKernelGGL(k_aggr, dim3(AB), dim3(256), 0, stream, h_bf, asrc, adst, b2, row_ptr, col, (float*)d_out, N);
}